// Round 3
// baseline (4288.134 us; speedup 1.0000x reference)
//
#include <hip/hip_runtime.h>
#include <hip/hip_fp16.h>
#include <math.h>

typedef unsigned short u16;
typedef float f32x4 __attribute__((ext_vector_type(4)));
typedef __bf16 bf16x8 __attribute__((ext_vector_type(8)));

__device__ __forceinline__ float b2f(u16 u) {
    union { unsigned int i; float f; } v; v.i = ((unsigned int)u) << 16; return v.f;
}
__device__ __forceinline__ u16 f2b(float f) {
    union { float f; unsigned int i; } v; v.f = f;
    unsigned int lsb = (v.i >> 16) & 1u;
    return (u16)((v.i + 0x7fffu + lsb) >> 16);   // RNE
}

// packed f16 atomic add via u32 CAS (correctness-first; upgrade later)
__device__ __forceinline__ void h2_cas_add(unsigned int* up, float x0, float x1) {
    unsigned int old = *(volatile unsigned int*)up, assumed;
    do {
        assumed = old;
        __half2 cur = *(__half2*)&assumed;
        __half2 nv = __halves2half2(__float2half(__half2float(__low2half(cur)) + x0),
                                    __float2half(__half2float(__high2half(cur)) + x1));
        old = atomicCAS(up, assumed, *(unsigned int*)&nv);
    } while (old != assumed);
}

// ---------------------------------------------------------------------------
// Scatter: agg[dst] += relu?(h[src]); one thread = 8 features (4 half2 CAS).
// F32SRC: source features are f32 (layer 0 reads x), else bf16 (H).
// ---------------------------------------------------------------------------
template<int F, bool RELU, bool F32SRC>
__global__ __launch_bounds__(256)
void k_scatter(const void* __restrict__ hsrc, const int* __restrict__ src,
               const int* __restrict__ dst, __half* __restrict__ agg, int E)
{
    constexpr int CPE = F / 8;
    int tid = blockIdx.x * 256 + threadIdx.x;
    if (tid >= E * CPE) return;
    int e = tid / CPE, c = tid % CPE;
    int s = src[e], d = dst[e];
    float xv[8];
    if (F32SRC) {
        const float* p = (const float*)hsrc + (size_t)s * F + c * 8;
        float4 a = *(const float4*)p, b = *(const float4*)(p + 4);
        xv[0]=a.x; xv[1]=a.y; xv[2]=a.z; xv[3]=a.w;
        xv[4]=b.x; xv[5]=b.y; xv[6]=b.z; xv[7]=b.w;
    } else {
        u16 vs[8] __attribute__((aligned(16)));
        *(uint4*)vs = *(const uint4*)((const u16*)hsrc + (size_t)s * F + c * 8);
#pragma unroll
        for (int i = 0; i < 8; ++i) xv[i] = b2f(vs[i]);
    }
    unsigned int* out = (unsigned int*)(agg + (size_t)d * F + c * 8);
#pragma unroll
    for (int i = 0; i < 4; ++i) {
        float x0 = xv[2 * i], x1 = xv[2 * i + 1];
        if (RELU) { x0 = fmaxf(x0, 0.f); x1 = fmaxf(x1, 0.f); }
        h2_cas_add(out + i, x0, x1);
    }
}

// transpose + f32->bf16 convert: out[n*K+k] = bf16(in[k*N+n])   (weights, tiny)
__global__ void k_T(const float* __restrict__ in, u16* __restrict__ out, int K, int N)
{
    int t = blockIdx.x * 256 + threadIdx.x;
    if (t >= K * N) return;
    int n = t / K, k = t % K;
    out[t] = f2b(in[k * N + n]);
}

// ---------------------------------------------------------------------------
// Fused GIN MLP: Hout(own 64 rows) = relu((relu?(A)+agg) @ Wa + ba) @ Wb + bb
// Block = 64 rows, 4 waves; wave = 16 rows x 256 cols (16 col-frags of 16x16).
// B-fragments read from pre-transposed bf16 weights in global (L2-hot).
// Hidden tile in LDS. In-place H update is safe: block touches only own rows.
// ---------------------------------------------------------------------------
template<int K, bool RELUIN, bool AF32>
__global__ __launch_bounds__(256)
void k_gin(const void* Ain, const __half* __restrict__ agg,
           const u16* __restrict__ WaT, const float* __restrict__ ba,
           const u16* __restrict__ WbT, const float* __restrict__ bb,
           u16* Hout)
{
    __shared__ u16 As[64 * 40];      // 32-k chunk of A, padded stride 40
    __shared__ u16 Hs[64 * 264];     // hidden tile (A-layout for phase 2)

    const int tid = threadIdx.x, lane = tid & 63, wave = tid >> 6;
    const int bm0 = blockIdx.x * 64;
    const int fm = lane & 15, fk = (lane >> 4) * 8;
    const int row0 = wave * 16;
    const int lc = lane & 15, lr = (lane >> 4) * 4;
    const int sr = tid >> 2, sc = tid & 3;

    f32x4 acc[16];
#pragma unroll
    for (int c = 0; c < 16; ++c) acc[c] = (f32x4){0.f, 0.f, 0.f, 0.f};

    // ---- phase 1: hidden = relu((relu?(A)+agg) @ Wa + ba) ----
    for (int k0 = 0; k0 < K; k0 += 32) {
        const size_t aoff = (size_t)(bm0 + sr) * K + k0 + sc * 8;
        float av[8];
        if (AF32) {
            const float* p = (const float*)Ain + aoff;
            float4 a = *(const float4*)p, b = *(const float4*)(p + 4);
            av[0]=a.x; av[1]=a.y; av[2]=a.z; av[3]=a.w;
            av[4]=b.x; av[5]=b.y; av[6]=b.z; av[7]=b.w;
        } else {
            u16 hb[8] __attribute__((aligned(16)));
            *(uint4*)hb = *(const uint4*)((const u16*)Ain + aoff);
#pragma unroll
            for (int i = 0; i < 8; ++i) av[i] = b2f(hb[i]);
        }
        __half ab[8] __attribute__((aligned(16)));
        *(uint4*)ab = *(const uint4*)(agg + aoff);
        u16 ob[8] __attribute__((aligned(16)));
#pragma unroll
        for (int i = 0; i < 8; ++i) {
            float v = av[i];
            if (RELUIN) v = fmaxf(v, 0.f);
            ob[i] = f2b(v + __half2float(ab[i]));
        }
        *(uint4*)&As[sr * 40 + sc * 8] = *(const uint4*)ob;
        __syncthreads();
        bf16x8 af = *(const bf16x8*)&As[(row0 + fm) * 40 + fk];
#pragma unroll
        for (int c = 0; c < 16; ++c) {
            bf16x8 bf = *(const bf16x8*)(WaT + (size_t)(c * 16 + fm) * K + k0 + fk);
            acc[c] = __builtin_amdgcn_mfma_f32_16x16x32_bf16(af, bf, acc[c], 0, 0, 0);
        }
        __syncthreads();
    }
    // epilogue 1 -> LDS hidden (C/D layout: col=lane&15, row=(lane>>4)*4+i)
#pragma unroll
    for (int c = 0; c < 16; ++c) {
        const int col = c * 16 + lc;
        const float bv = ba[col];
#pragma unroll
        for (int i = 0; i < 4; ++i) {
            const int r = row0 + lr + i;
            Hs[r * 264 + col] = f2b(fmaxf(acc[c][i] + bv, 0.f));
        }
    }
    __syncthreads();

    // ---- phase 2: out = hidden @ Wb + bb ----
    f32x4 acc2[16];
#pragma unroll
    for (int c = 0; c < 16; ++c) acc2[c] = (f32x4){0.f, 0.f, 0.f, 0.f};
    for (int k0 = 0; k0 < 256; k0 += 32) {
        bf16x8 af = *(const bf16x8*)&Hs[(row0 + fm) * 264 + k0 + fk];
#pragma unroll
        for (int c = 0; c < 16; ++c) {
            bf16x8 bf = *(const bf16x8*)(WbT + (size_t)(c * 16 + fm) * 256 + k0 + fk);
            acc2[c] = __builtin_amdgcn_mfma_f32_16x16x32_bf16(af, bf, acc2[c], 0, 0, 0);
        }
    }
#pragma unroll
    for (int c = 0; c < 16; ++c) {
        const int col = c * 16 + lc;
        const float bv = bb[col];
#pragma unroll
        for (int i = 0; i < 4; ++i) {
            const int r = bm0 + row0 + lr + i;
            Hout[(size_t)r * 256 + col] = f2b(acc2[c][i] + bv);
        }
    }
}

// ---------------------------------------------------------------------------
// Classifier linear: C[f32] = leaky(A[bf16] @ WT^T), NOUT=512 cols, K=256.
// ---------------------------------------------------------------------------
__global__ __launch_bounds__(256)
void k_lin(const u16* __restrict__ A, const u16* __restrict__ WT,
           float* __restrict__ C)
{
    __shared__ u16 As[64 * 40];
    const int tid = threadIdx.x, lane = tid & 63, wave = tid >> 6;
    const int bm0 = blockIdx.x * 64;
    const int fm = lane & 15, fk = (lane >> 4) * 8;
    const int row0 = wave * 16;
    const int lc = lane & 15, lr = (lane >> 4) * 4;
    const int sr = tid >> 2, sc = tid & 3;
    constexpr int K = 256, CF = 32;

    f32x4 acc[CF];
#pragma unroll
    for (int c = 0; c < CF; ++c) acc[c] = (f32x4){0.f, 0.f, 0.f, 0.f};

    for (int k0 = 0; k0 < K; k0 += 32) {
        *(uint4*)&As[sr * 40 + sc * 8] =
            *(const uint4*)(A + (size_t)(bm0 + sr) * K + k0 + sc * 8);
        __syncthreads();
        bf16x8 af = *(const bf16x8*)&As[(row0 + fm) * 40 + fk];
#pragma unroll
        for (int c = 0; c < CF; ++c) {
            bf16x8 bf = *(const bf16x8*)(WT + (size_t)(c * 16 + fm) * K + k0 + fk);
            acc[c] = __builtin_amdgcn_mfma_f32_16x16x32_bf16(af, bf, acc[c], 0, 0, 0);
        }
        __syncthreads();
    }
#pragma unroll
    for (int c = 0; c < CF; ++c) {
        const int col = c * 16 + lc;
#pragma unroll
        for (int i = 0; i < 4; ++i) {
            const int r = bm0 + row0 + lr + i;
            float v = acc[c][i];
            v = (v >= 0.f) ? v : 0.01f * v;   // leaky
            C[(size_t)r * 512 + col] = v;
        }
    }
}

// ---------------------------------------------------------------------------
// Head kernels (f32)
// ---------------------------------------------------------------------------
__global__ void k_pool(const u16* __restrict__ H, u16* __restrict__ Xc)
{
    int c = blockIdx.x, f = threadIdx.x;          // 8192 blocks x 256
    const u16* p = H + (size_t)c * 25 * 256 + f;
    float s = 0.f;
#pragma unroll
    for (int j = 0; j < 25; ++j) s += b2f(p[j * 256]);
    Xc[(size_t)c * 256 + f] = f2b(s / 25.0f);
}

__global__ void k_setpool(const float* __restrict__ T, float* __restrict__ Tp)
{
    int tid = blockIdx.x * 256 + threadIdx.x;     // 4096*64
    int b = tid >> 6, s = tid & 63;
    float acc = 0.f;
#pragma unroll
    for (int c = 0; c < 2; ++c) {
        const float* row = T + ((size_t)(b * 2 + c)) * 512 + s;
        float mx = row[0];
#pragma unroll
        for (int m = 1; m < 8; ++m) mx = fmaxf(mx, row[m * 64]);
        acc += mx;
    }
    Tp[tid] = acc;
}

__global__ void k_fc1(const float* __restrict__ Tp, const float* __restrict__ w,
                      const float* __restrict__ b, float* __restrict__ T1)
{
    int tid = blockIdx.x * 256 + threadIdx.x;     // 4096*32
    int bb = tid >> 5, j = tid & 31;
    float s = b[j];
#pragma unroll
    for (int k = 0; k < 64; ++k) s += Tp[bb * 64 + k] * w[k * 32 + j];
    T1[tid] = s;
}

__global__ void k_bnstats(const float* __restrict__ T1, float* __restrict__ stats)
{
    __shared__ float r1[256], r2[256];
    const int j = blockIdx.x, t = threadIdx.x;    // 32 blocks
    float s = 0.f, ss = 0.f;
    for (int b = t; b < 4096; b += 256) {
        float v = T1[b * 32 + j];
        s += v; ss += v * v;
    }
    r1[t] = s; r2[t] = ss;
    __syncthreads();
    for (int off = 128; off > 0; off >>= 1) {
        if (t < off) { r1[t] += r1[t + off]; r2[t] += r2[t + off]; }
        __syncthreads();
    }
    if (t == 0) {
        float mu  = r1[0] * (1.f / 4096.f);
        float var = r2[0] * (1.f / 4096.f) - mu * mu;
        stats[j]      = mu;
        stats[32 + j] = 1.f / sqrtf(var + 1e-5f);
    }
}

__global__ void k_head(const float* __restrict__ T1, const float* __restrict__ stats,
                       const float* __restrict__ g, const float* __restrict__ bb,
                       const float* __restrict__ w2, const float* __restrict__ b2,
                       float* __restrict__ out)
{
    const int b = blockIdx.x * 256 + threadIdx.x; // 4096
    float l0 = b2[0], l1 = b2[1];
#pragma unroll
    for (int j = 0; j < 32; ++j) {
        float v = (T1[b * 32 + j] - stats[j]) * stats[32 + j] * g[j] + bb[j];
        v = (v >= 0.f) ? v : 0.01f * v;
        l0 += v * w2[j * 2];
        l1 += v * w2[j * 2 + 1];
    }
    float mx  = fmaxf(l0, l1);
    float lse = mx + logf(expf(l0 - mx) + expf(l1 - mx));
    out[b * 2]     = l0 - lse;
    out[b * 2 + 1] = l1 - lse;
}

// ---------------------------------------------------------------------------
extern "C" void kernel_launch(void* const* d_in, const int* in_sizes, int n_in,
                              void* d_out, int out_size, void* d_ws, size_t ws_size,
                              hipStream_t stream)
{
    (void)n_in; (void)out_size; (void)ws_size;
    constexpr int NN = 204800, NCOMP = 8192, NGRAPH = 4096;

    const float* x    = (const float*)d_in[0];
    const float* w0a  = (const float*)d_in[1];
    const float* b0a  = (const float*)d_in[2];
    const float* w0b  = (const float*)d_in[3];
    const float* b0b  = (const float*)d_in[4];
    const float* wra  = (const float*)d_in[5];
    const float* bra  = (const float*)d_in[6];
    const float* wrb  = (const float*)d_in[7];
    const float* brb  = (const float*)d_in[8];
    const float* Wc   = (const float*)d_in[9];
    const float* f1w  = (const float*)d_in[10];
    const float* f1b  = (const float*)d_in[11];
    const float* bng  = (const float*)d_in[12];
    const float* bnb  = (const float*)d_in[13];
    const float* f2w  = (const float*)d_in[14];
    const float* f2bb = (const float*)d_in[15];
    const int* ei   = (const int*)d_in[16];
    const int  E    = in_sizes[16] / 2;           // 409600
    const int* src  = ei;
    const int* dst  = ei + E;

    // ---- workspace layout (total ~201 MiB) ----
    char* ws = (char*)d_ws;
    __half* AGG = (__half*)ws;                               // [N,256] f16, 100 MiB
    u16*    H   = (u16*)(ws + (size_t)104857600);            // [N,256] bf16, 100 MiB
    u16*    wt  = (u16*)(ws + (size_t)209715200);            // transposed bf16 weights, 1 MiB
    u16 *WT0 = wt, *WT1 = wt + 65536, *WT2 = wt + 131072, *WT3 = wt + 196608,
        *WT4 = wt + 262144, *WT5 = wt + 327680, *WT6 = wt + 393216;
    // head scratch reuses dead AGG region:
    u16*   Xc    = (u16*)ws;                                 // [8192,256] bf16
    float* Tfull = (float*)(ws + (size_t)16777216);          // [8192,512] f32
    float* Tp    = (float*)(ws + (size_t)33554432);          // [4096,64]
    float* T1    = (float*)(ws + (size_t)41943040);          // [4096,32]
    float* stats = (float*)(ws + (size_t)46137344);          // mu[32], rstd[32]

    const dim3 blk(256);

    // ---- pre-transpose weights (f32 -> bf16) ----
    k_T<<<128, blk, 0, stream>>>(w0a, WT0, 128, 256);
    k_T<<<256, blk, 0, stream>>>(w0b, WT1, 256, 256);
    k_T<<<256, blk, 0, stream>>>(wra,          WT2, 256, 256);
    k_T<<<256, blk, 0, stream>>>(wra + 65536,  WT3, 256, 256);
    k_T<<<256, blk, 0, stream>>>(wrb,          WT4, 256, 256);
    k_T<<<256, blk, 0, stream>>>(wrb + 65536,  WT5, 256, 256);
    k_T<<<512, blk, 0, stream>>>(Wc, WT6, 256, 512);

    // ---- layer 0 (K=128, A = x f32, no input relu) ----
    hipMemsetAsync(AGG, 0, (size_t)NN * 128 * 2, stream);
    k_scatter<128, false, true><<<(E * 16) / 256, blk, 0, stream>>>(x, src, dst, AGG, E);
    k_gin<128, false, true><<<NN / 64, blk, 0, stream>>>(x, AGG, WT0, b0a, WT1, b0b, H);

    // ---- layers 1..2 (K=256, A = H bf16, relu on layer input) ----
    const u16* WA[2] = {WT2, WT3};
    const u16* WB[2] = {WT4, WT5};
    for (int l = 0; l < 2; ++l) {
        hipMemsetAsync(AGG, 0, (size_t)NN * 256 * 2, stream);
        k_scatter<256, true, false><<<(E * 32) / 256, blk, 0, stream>>>(H, src, dst, AGG, E);
        k_gin<256, true, false><<<NN / 64, blk, 0, stream>>>(
            H, AGG, WA[l], bra + (size_t)l * 256, WB[l], brb + (size_t)l * 256, H);
    }

    // ---- head ----
    k_pool<<<NCOMP, blk, 0, stream>>>(H, Xc);
    k_lin<<<NCOMP / 64, blk, 0, stream>>>(Xc, WT6, Tfull);
    k_setpool<<<(NGRAPH * 64) / 256, blk, 0, stream>>>(Tfull, Tp);
    k_fc1<<<(NGRAPH * 32) / 256, blk, 0, stream>>>(Tp, f1w, f1b, T1);
    k_bnstats<<<32, blk, 0, stream>>>(T1, stats);
    k_head<<<NGRAPH / 256, blk, 0, stream>>>(T1, stats, bng, bnb, f2w, f2bb, (float*)d_out);
}

// Round 4
// 1696.772 us; speedup vs baseline: 2.5272x; 2.5272x over previous
//
#include <hip/hip_runtime.h>
#include <hip/hip_fp16.h>
#include <math.h>

typedef unsigned short u16;
typedef float f32x4 __attribute__((ext_vector_type(4)));
typedef __bf16 bf16x8 __attribute__((ext_vector_type(8)));

__device__ __forceinline__ float b2f(u16 u) {
    union { unsigned int i; float f; } v; v.i = ((unsigned int)u) << 16; return v.f;
}
__device__ __forceinline__ u16 f2b(float f) {
    union { float f; unsigned int i; } v; v.f = f;
    unsigned int lsb = (v.i >> 16) & 1u;
    return (u16)((v.i + 0x7fffu + lsb) >> 16);   // RNE
}

// ---------------------------------------------------------------------------
// CSR build: counts -> block scan -> global scan -> fill
// ---------------------------------------------------------------------------
__global__ __launch_bounds__(256)
void k_count(const int* __restrict__ dst, int* __restrict__ cnt, int E)
{
    int e = blockIdx.x * 256 + threadIdx.x;
    if (e < E) atomicAdd(&cnt[dst[e]], 1);
}

// per-256-block exclusive scan; bsum[b] = block total
__global__ __launch_bounds__(256)
void k_scan1(const int* __restrict__ cnt, int* __restrict__ rowptr,
             int* __restrict__ bsum, int N)
{
    __shared__ int s[256];
    int t = threadIdx.x, i = blockIdx.x * 256 + t;
    int v = (i < N) ? cnt[i] : 0;
    s[t] = v;
    __syncthreads();
#pragma unroll
    for (int off = 1; off < 256; off <<= 1) {
        int add = (t >= off) ? s[t - off] : 0;
        __syncthreads();
        s[t] += add;
        __syncthreads();
    }
    if (i < N) rowptr[i] = s[t] - v;          // exclusive within block
    if (t == 255) bsum[blockIdx.x] = s[255];
}

// exclusive scan of bsum[0..nb) (nb <= 1024), 256 threads x 4 elems
__global__ __launch_bounds__(256)
void k_scan2(const int* __restrict__ bsum, int* __restrict__ bscan, int nb)
{
    __shared__ int s[256];
    int t = threadIdx.x;
    int g[4], e[4];
    int base = t * 4;
#pragma unroll
    for (int j = 0; j < 4; ++j) g[j] = (base + j < nb) ? bsum[base + j] : 0;
    e[0] = 0; e[1] = g[0]; e[2] = g[0] + g[1]; e[3] = g[0] + g[1] + g[2];
    int tsum = e[3] + g[3];
    s[t] = tsum;
    __syncthreads();
#pragma unroll
    for (int off = 1; off < 256; off <<= 1) {
        int add = (t >= off) ? s[t - off] : 0;
        __syncthreads();
        s[t] += add;
        __syncthreads();
    }
    int texcl = s[t] - tsum;
#pragma unroll
    for (int j = 0; j < 4; ++j)
        if (base + j < nb) bscan[base + j] = texcl + e[j];
}

__global__ __launch_bounds__(256)
void k_scan3(int* __restrict__ rowptr, const int* __restrict__ bscan,
             int* __restrict__ cursor, int N)
{
    int i = blockIdx.x * 256 + threadIdx.x;
    if (i >= N) return;
    int r = rowptr[i] + bscan[i >> 8];
    rowptr[i] = r;
    cursor[i] = r;
}

__global__ __launch_bounds__(256)
void k_fill(const int* __restrict__ src, const int* __restrict__ dst,
            int* __restrict__ cursor, int* __restrict__ col, int E)
{
    int e = blockIdx.x * 256 + threadIdx.x;
    if (e >= E) return;
    int pos = atomicAdd(&cursor[dst[e]], 1);
    col[pos] = src[e];
}

// ---------------------------------------------------------------------------
// Gather aggregation: agg[i] = sum_{j in in(i)} relu?(h[col[j]]); f16 out.
// CPE consecutive threads handle one node (16B chunks) -> coalesced row reads.
// No memset needed: every element written (deg-0 nodes write zeros).
// ---------------------------------------------------------------------------
template<int F, bool RELU, bool F32SRC>
__global__ __launch_bounds__(256)
void k_gather(const void* __restrict__ hsrc, const int* __restrict__ cnt,
              const int* __restrict__ rowptr, const int* __restrict__ col,
              __half* __restrict__ agg, int N)
{
    constexpr int CPE = F / 8;
    int tid = blockIdx.x * 256 + threadIdx.x;
    int node = tid / CPE, c = tid % CPE;
    if (node >= N) return;
    int n = cnt[node], rp = rowptr[node];
    float acc[8] = {0.f, 0.f, 0.f, 0.f, 0.f, 0.f, 0.f, 0.f};
    for (int j = 0; j < n; ++j) {
        int s = col[rp + j];
        if (F32SRC) {
            const float* p = (const float*)hsrc + (size_t)s * F + c * 8;
            float4 a = *(const float4*)p, b = *(const float4*)(p + 4);
            float xv[8] = {a.x, a.y, a.z, a.w, b.x, b.y, b.z, b.w};
#pragma unroll
            for (int i = 0; i < 8; ++i) acc[i] += RELU ? fmaxf(xv[i], 0.f) : xv[i];
        } else {
            u16 vs[8] __attribute__((aligned(16)));
            *(uint4*)vs = *(const uint4*)((const u16*)hsrc + (size_t)s * F + c * 8);
#pragma unroll
            for (int i = 0; i < 8; ++i) {
                float x = b2f(vs[i]);
                acc[i] += RELU ? fmaxf(x, 0.f) : x;
            }
        }
    }
    __half ob[8] __attribute__((aligned(16)));
#pragma unroll
    for (int i = 0; i < 8; ++i) ob[i] = __float2half(acc[i]);
    *(uint4*)(agg + (size_t)node * F + c * 8) = *(const uint4*)ob;
}

// transpose + f32->bf16 convert: out[n*K+k] = bf16(in[k*N+n])   (weights, tiny)
__global__ void k_T(const float* __restrict__ in, u16* __restrict__ out, int K, int N)
{
    int t = blockIdx.x * 256 + threadIdx.x;
    if (t >= K * N) return;
    int n = t / K, k = t % K;
    out[t] = f2b(in[k * N + n]);
}

// ---------------------------------------------------------------------------
// Fused GIN MLP: Hout(own 64 rows) = relu((relu?(A)+agg) @ Wa + ba) @ Wb + bb
// ---------------------------------------------------------------------------
template<int K, bool RELUIN, bool AF32>
__global__ __launch_bounds__(256)
void k_gin(const void* Ain, const __half* __restrict__ agg,
           const u16* __restrict__ WaT, const float* __restrict__ ba,
           const u16* __restrict__ WbT, const float* __restrict__ bb,
           u16* Hout)
{
    __shared__ u16 As[64 * 40];      // 32-k chunk of A, padded stride 40
    __shared__ u16 Hs[64 * 264];     // hidden tile (A-layout for phase 2)

    const int tid = threadIdx.x, lane = tid & 63, wave = tid >> 6;
    const int bm0 = blockIdx.x * 64;
    const int fm = lane & 15, fk = (lane >> 4) * 8;
    const int row0 = wave * 16;
    const int lc = lane & 15, lr = (lane >> 4) * 4;
    const int sr = tid >> 2, sc = tid & 3;

    f32x4 acc[16];
#pragma unroll
    for (int c = 0; c < 16; ++c) acc[c] = (f32x4){0.f, 0.f, 0.f, 0.f};

    // ---- phase 1: hidden = relu((relu?(A)+agg) @ Wa + ba) ----
    for (int k0 = 0; k0 < K; k0 += 32) {
        const size_t aoff = (size_t)(bm0 + sr) * K + k0 + sc * 8;
        float av[8];
        if (AF32) {
            const float* p = (const float*)Ain + aoff;
            float4 a = *(const float4*)p, b = *(const float4*)(p + 4);
            av[0]=a.x; av[1]=a.y; av[2]=a.z; av[3]=a.w;
            av[4]=b.x; av[5]=b.y; av[6]=b.z; av[7]=b.w;
        } else {
            u16 hb[8] __attribute__((aligned(16)));
            *(uint4*)hb = *(const uint4*)((const u16*)Ain + aoff);
#pragma unroll
            for (int i = 0; i < 8; ++i) av[i] = b2f(hb[i]);
        }
        __half ab[8] __attribute__((aligned(16)));
        *(uint4*)ab = *(const uint4*)(agg + aoff);
        u16 ob[8] __attribute__((aligned(16)));
#pragma unroll
        for (int i = 0; i < 8; ++i) {
            float v = av[i];
            if (RELUIN) v = fmaxf(v, 0.f);
            ob[i] = f2b(v + __half2float(ab[i]));
        }
        *(uint4*)&As[sr * 40 + sc * 8] = *(const uint4*)ob;
        __syncthreads();
        bf16x8 af = *(const bf16x8*)&As[(row0 + fm) * 40 + fk];
#pragma unroll
        for (int c = 0; c < 16; ++c) {
            bf16x8 bf = *(const bf16x8*)(WaT + (size_t)(c * 16 + fm) * K + k0 + fk);
            acc[c] = __builtin_amdgcn_mfma_f32_16x16x32_bf16(af, bf, acc[c], 0, 0, 0);
        }
        __syncthreads();
    }
    // epilogue 1 -> LDS hidden (C/D layout: col=lane&15, row=(lane>>4)*4+i)
#pragma unroll
    for (int c = 0; c < 16; ++c) {
        const int col = c * 16 + lc;
        const float bv = ba[col];
#pragma unroll
        for (int i = 0; i < 4; ++i) {
            const int r = row0 + lr + i;
            Hs[r * 264 + col] = f2b(fmaxf(acc[c][i] + bv, 0.f));
        }
    }
    __syncthreads();

    // ---- phase 2: out = hidden @ Wb + bb ----
    f32x4 acc2[16];
#pragma unroll
    for (int c = 0; c < 16; ++c) acc2[c] = (f32x4){0.f, 0.f, 0.f, 0.f};
    for (int k0 = 0; k0 < 256; k0 += 32) {
        bf16x8 af = *(const bf16x8*)&Hs[(row0 + fm) * 264 + k0 + fk];
#pragma unroll
        for (int c = 0; c < 16; ++c) {
            bf16x8 bf = *(const bf16x8*)(WbT + (size_t)(c * 16 + fm) * 256 + k0 + fk);
            acc2[c] = __builtin_amdgcn_mfma_f32_16x16x32_bf16(af, bf, acc2[c], 0, 0, 0);
        }
    }
#pragma unroll
    for (int c = 0; c < 16; ++c) {
        const int col = c * 16 + lc;
        const float bv = bb[col];
#pragma unroll
        for (int i = 0; i < 4; ++i) {
            const int r = bm0 + row0 + lr + i;
            Hout[(size_t)r * 256 + col] = f2b(acc2[c][i] + bv);
        }
    }
}

// ---------------------------------------------------------------------------
// Classifier linear: C[f32] = leaky(A[bf16] @ WT^T), NOUT=512 cols, K=256.
// ---------------------------------------------------------------------------
__global__ __launch_bounds__(256)
void k_lin(const u16* __restrict__ A, const u16* __restrict__ WT,
           float* __restrict__ C)
{
    __shared__ u16 As[64 * 40];
    const int tid = threadIdx.x, lane = tid & 63, wave = tid >> 6;
    const int bm0 = blockIdx.x * 64;
    const int fm = lane & 15, fk = (lane >> 4) * 8;
    const int row0 = wave * 16;
    const int lc = lane & 15, lr = (lane >> 4) * 4;
    const int sr = tid >> 2, sc = tid & 3;
    constexpr int K = 256, CF = 32;

    f32x4 acc[CF];
#pragma unroll
    for (int c = 0; c < CF; ++c) acc[c] = (f32x4){0.f, 0.f, 0.f, 0.f};

    for (int k0 = 0; k0 < K; k0 += 32) {
        *(uint4*)&As[sr * 40 + sc * 8] =
            *(const uint4*)(A + (size_t)(bm0 + sr) * K + k0 + sc * 8);
        __syncthreads();
        bf16x8 af = *(const bf16x8*)&As[(row0 + fm) * 40 + fk];
#pragma unroll
        for (int c = 0; c < CF; ++c) {
            bf16x8 bf = *(const bf16x8*)(WT + (size_t)(c * 16 + fm) * K + k0 + fk);
            acc[c] = __builtin_amdgcn_mfma_f32_16x16x32_bf16(af, bf, acc[c], 0, 0, 0);
        }
        __syncthreads();
    }
#pragma unroll
    for (int c = 0; c < CF; ++c) {
        const int col = c * 16 + lc;
#pragma unroll
        for (int i = 0; i < 4; ++i) {
            const int r = bm0 + row0 + lr + i;
            float v = acc[c][i];
            v = (v >= 0.f) ? v : 0.01f * v;   // leaky
            C[(size_t)r * 512 + col] = v;
        }
    }
}

// ---------------------------------------------------------------------------
// Head kernels (f32)
// ---------------------------------------------------------------------------
__global__ void k_pool(const u16* __restrict__ H, u16* __restrict__ Xc)
{
    int c = blockIdx.x, f = threadIdx.x;          // 8192 blocks x 256
    const u16* p = H + (size_t)c * 25 * 256 + f;
    float s = 0.f;
#pragma unroll
    for (int j = 0; j < 25; ++j) s += b2f(p[j * 256]);
    Xc[(size_t)c * 256 + f] = f2b(s / 25.0f);
}

__global__ void k_setpool(const float* __restrict__ T, float* __restrict__ Tp)
{
    int tid = blockIdx.x * 256 + threadIdx.x;     // 4096*64
    int b = tid >> 6, s = tid & 63;
    float acc = 0.f;
#pragma unroll
    for (int c = 0; c < 2; ++c) {
        const float* row = T + ((size_t)(b * 2 + c)) * 512 + s;
        float mx = row[0];
#pragma unroll
        for (int m = 1; m < 8; ++m) mx = fmaxf(mx, row[m * 64]);
        acc += mx;
    }
    Tp[tid] = acc;
}

__global__ void k_fc1(const float* __restrict__ Tp, const float* __restrict__ w,
                      const float* __restrict__ b, float* __restrict__ T1)
{
    int tid = blockIdx.x * 256 + threadIdx.x;     // 4096*32
    int bb = tid >> 5, j = tid & 31;
    float s = b[j];
#pragma unroll
    for (int k = 0; k < 64; ++k) s += Tp[bb * 64 + k] * w[k * 32 + j];
    T1[tid] = s;
}

__global__ void k_bnstats(const float* __restrict__ T1, float* __restrict__ stats)
{
    __shared__ float r1[256], r2[256];
    const int j = blockIdx.x, t = threadIdx.x;    // 32 blocks
    float s = 0.f, ss = 0.f;
    for (int b = t; b < 4096; b += 256) {
        float v = T1[b * 32 + j];
        s += v; ss += v * v;
    }
    r1[t] = s; r2[t] = ss;
    __syncthreads();
    for (int off = 128; off > 0; off >>= 1) {
        if (t < off) { r1[t] += r1[t + off]; r2[t] += r2[t + off]; }
        __syncthreads();
    }
    if (t == 0) {
        float mu  = r1[0] * (1.f / 4096.f);
        float var = r2[0] * (1.f / 4096.f) - mu * mu;
        stats[j]      = mu;
        stats[32 + j] = 1.f / sqrtf(var + 1e-5f);
    }
}

__global__ void k_head(const float* __restrict__ T1, const float* __restrict__ stats,
                       const float* __restrict__ g, const float* __restrict__ bb,
                       const float* __restrict__ w2, const float* __restrict__ b2,
                       float* __restrict__ out)
{
    const int b = blockIdx.x * 256 + threadIdx.x; // 4096
    float l0 = b2[0], l1 = b2[1];
#pragma unroll
    for (int j = 0; j < 32; ++j) {
        float v = (T1[b * 32 + j] - stats[j]) * stats[32 + j] * g[j] + bb[j];
        v = (v >= 0.f) ? v : 0.01f * v;
        l0 += v * w2[j * 2];
        l1 += v * w2[j * 2 + 1];
    }
    float mx  = fmaxf(l0, l1);
    float lse = mx + logf(expf(l0 - mx) + expf(l1 - mx));
    out[b * 2]     = l0 - lse;
    out[b * 2 + 1] = l1 - lse;
}

// ---------------------------------------------------------------------------
extern "C" void kernel_launch(void* const* d_in, const int* in_sizes, int n_in,
                              void* d_out, int out_size, void* d_ws, size_t ws_size,
                              hipStream_t stream)
{
    (void)n_in; (void)out_size; (void)ws_size;
    constexpr int NN = 204800, NCOMP = 8192, NGRAPH = 4096;

    const float* x    = (const float*)d_in[0];
    const float* w0a  = (const float*)d_in[1];
    const float* b0a  = (const float*)d_in[2];
    const float* w0b  = (const float*)d_in[3];
    const float* b0b  = (const float*)d_in[4];
    const float* wra  = (const float*)d_in[5];
    const float* bra  = (const float*)d_in[6];
    const float* wrb  = (const float*)d_in[7];
    const float* brb  = (const float*)d_in[8];
    const float* Wc   = (const float*)d_in[9];
    const float* f1w  = (const float*)d_in[10];
    const float* f1b  = (const float*)d_in[11];
    const float* bng  = (const float*)d_in[12];
    const float* bnb  = (const float*)d_in[13];
    const float* f2w  = (const float*)d_in[14];
    const float* f2bb = (const float*)d_in[15];
    const int* ei   = (const int*)d_in[16];
    const int  E    = in_sizes[16] / 2;           // 409600
    const int* src  = ei;
    const int* dst  = ei + E;

    // ---- workspace layout (~205 MiB) ----
    char* ws = (char*)d_ws;
    __half* AGG = (__half*)ws;                               // [N,256] f16, 100 MiB
    u16*    H   = (u16*)(ws + (size_t)104857600);            // [N,256] bf16, 100 MiB
    u16*    wt  = (u16*)(ws + (size_t)209715200);            // transposed bf16 weights, 1 MiB
    u16 *WT0 = wt, *WT1 = wt + 65536, *WT2 = wt + 131072, *WT3 = wt + 196608,
        *WT4 = wt + 262144, *WT5 = wt + 327680, *WT6 = wt + 393216;
    // CSR arrays after weights:
    char* csr = ws + (size_t)210763776;
    int* cnt    = (int*)csr;                                 // [N]
    int* rowptr = (int*)(csr + 819200);                      // [N]
    int* cursor = (int*)(csr + 1638400);                     // [N]
    int* col    = (int*)(csr + 2457600);                     // [E]
    int* bsum   = (int*)(csr + 4096000);                     // [1024]
    int* bscan  = (int*)(csr + 4100096);                     // [1024]
    // head scratch reuses dead AGG region:
    u16*   Xc    = (u16*)ws;                                 // [8192,256] bf16
    float* Tfull = (float*)(ws + (size_t)16777216);          // [8192,512] f32
    float* Tp    = (float*)(ws + (size_t)33554432);          // [4096,64]
    float* T1    = (float*)(ws + (size_t)41943040);          // [4096,32]
    float* stats = (float*)(ws + (size_t)46137344);          // mu[32], rstd[32]

    const dim3 blk(256);
    const int NB = NN / 256;                                  // 800 scan blocks

    // ---- CSR build (once, reused by all 3 layers) ----
    hipMemsetAsync(cnt, 0, NN * 4, stream);
    k_count<<<(E + 255) / 256, blk, 0, stream>>>(dst, cnt, E);
    k_scan1<<<NB, blk, 0, stream>>>(cnt, rowptr, bsum, NN);
    k_scan2<<<1, blk, 0, stream>>>(bsum, bscan, NB);
    k_scan3<<<NB, blk, 0, stream>>>(rowptr, bscan, cursor, NN);
    k_fill<<<(E + 255) / 256, blk, 0, stream>>>(src, dst, cursor, col, E);

    // ---- pre-transpose weights (f32 -> bf16) ----
    k_T<<<128, blk, 0, stream>>>(w0a, WT0, 128, 256);
    k_T<<<256, blk, 0, stream>>>(w0b, WT1, 256, 256);
    k_T<<<256, blk, 0, stream>>>(wra,          WT2, 256, 256);
    k_T<<<256, blk, 0, stream>>>(wra + 65536,  WT3, 256, 256);
    k_T<<<256, blk, 0, stream>>>(wrb,          WT4, 256, 256);
    k_T<<<256, blk, 0, stream>>>(wrb + 65536,  WT5, 256, 256);
    k_T<<<512, blk, 0, stream>>>(Wc, WT6, 256, 512);

    // ---- layer 0 (K=128, A = x f32, no relu) ----
    k_gather<128, false, true><<<(NN * 16) / 256, blk, 0, stream>>>(x, cnt, rowptr, col, AGG, NN);
    k_gin<128, false, true><<<NN / 64, blk, 0, stream>>>(x, AGG, WT0, b0a, WT1, b0b, H);

    // ---- layers 1..2 (K=256, A = H bf16, relu on layer input) ----
    const u16* WA[2] = {WT2, WT3};
    const u16* WB[2] = {WT4, WT5};
    for (int l = 0; l < 2; ++l) {
        k_gather<256, true, false><<<(NN * 32) / 256, blk, 0, stream>>>(H, cnt, rowptr, col, AGG, NN);
        k_gin<256, true, false><<<NN / 64, blk, 0, stream>>>(
            H, AGG, WA[l], bra + (size_t)l * 256, WB[l], brb + (size_t)l * 256, H);
    }

    // ---- head ----
    k_pool<<<NCOMP, blk, 0, stream>>>(H, Xc);
    k_lin<<<NCOMP / 64, blk, 0, stream>>>(Xc, WT6, Tfull);
    k_setpool<<<(NGRAPH * 64) / 256, blk, 0, stream>>>(Tfull, Tp);
    k_fc1<<<(NGRAPH * 32) / 256, blk, 0, stream>>>(Tp, f1w, f1b, T1);
    k_bnstats<<<32, blk, 0, stream>>>(T1, stats);
    k_head<<<NGRAPH / 256, blk, 0, stream>>>(T1, stats, bng, bnb, f2w, f2bb, (float*)d_out);
}

// Round 5
// 900.824 us; speedup vs baseline: 4.7602x; 1.8836x over previous
//
#include <hip/hip_runtime.h>
#include <hip/hip_fp16.h>
#include <math.h>

typedef unsigned short u16;
typedef float f32x4 __attribute__((ext_vector_type(4)));
typedef __bf16 bf16x8 __attribute__((ext_vector_type(8)));

__device__ __forceinline__ float b2f(u16 u) {
    union { unsigned int i; float f; } v; v.i = ((unsigned int)u) << 16; return v.f;
}
__device__ __forceinline__ u16 f2b(float f) {
    union { float f; unsigned int i; } v; v.f = f;
    unsigned int lsb = (v.i >> 16) & 1u;
    return (u16)((v.i + 0x7fffu + lsb) >> 16);   // RNE
}

// ---------------------------------------------------------------------------
// CSR build: counts -> block scan -> global scan -> fill
// ---------------------------------------------------------------------------
__global__ __launch_bounds__(256)
void k_count(const int* __restrict__ dst, int* __restrict__ cnt, int E)
{
    int e = blockIdx.x * 256 + threadIdx.x;
    if (e < E) atomicAdd(&cnt[dst[e]], 1);
}

__global__ __launch_bounds__(256)
void k_scan1(const int* __restrict__ cnt, int* __restrict__ rowptr,
             int* __restrict__ bsum, int N)
{
    __shared__ int s[256];
    int t = threadIdx.x, i = blockIdx.x * 256 + t;
    int v = (i < N) ? cnt[i] : 0;
    s[t] = v;
    __syncthreads();
#pragma unroll
    for (int off = 1; off < 256; off <<= 1) {
        int add = (t >= off) ? s[t - off] : 0;
        __syncthreads();
        s[t] += add;
        __syncthreads();
    }
    if (i < N) rowptr[i] = s[t] - v;
    if (t == 255) bsum[blockIdx.x] = s[255];
}

__global__ __launch_bounds__(256)
void k_scan2(const int* __restrict__ bsum, int* __restrict__ bscan, int nb)
{
    __shared__ int s[256];
    int t = threadIdx.x;
    int g[4], e[4];
    int base = t * 4;
#pragma unroll
    for (int j = 0; j < 4; ++j) g[j] = (base + j < nb) ? bsum[base + j] : 0;
    e[0] = 0; e[1] = g[0]; e[2] = g[0] + g[1]; e[3] = g[0] + g[1] + g[2];
    int tsum = e[3] + g[3];
    s[t] = tsum;
    __syncthreads();
#pragma unroll
    for (int off = 1; off < 256; off <<= 1) {
        int add = (t >= off) ? s[t - off] : 0;
        __syncthreads();
        s[t] += add;
        __syncthreads();
    }
    int texcl = s[t] - tsum;
#pragma unroll
    for (int j = 0; j < 4; ++j)
        if (base + j < nb) bscan[base + j] = texcl + e[j];
}

__global__ __launch_bounds__(256)
void k_scan3(int* __restrict__ rowptr, const int* __restrict__ bscan,
             int* __restrict__ cursor, int N)
{
    int i = blockIdx.x * 256 + threadIdx.x;
    if (i >= N) return;
    int r = rowptr[i] + bscan[i >> 8];
    rowptr[i] = r;
    cursor[i] = r;
}

__global__ __launch_bounds__(256)
void k_fill(const int* __restrict__ src, const int* __restrict__ dst,
            int* __restrict__ cursor, int* __restrict__ col, int E)
{
    int e = blockIdx.x * 256 + threadIdx.x;
    if (e >= E) return;
    int pos = atomicAdd(&cursor[dst[e]], 1);
    col[pos] = src[e];
}

// ---------------------------------------------------------------------------
// Gather aggregation: agg[i] = sum_{j in in(i)} relu?(h[col[j]]); f16 out.
// ---------------------------------------------------------------------------
template<int F, bool RELU, bool F32SRC>
__global__ __launch_bounds__(256)
void k_gather(const void* __restrict__ hsrc, const int* __restrict__ cnt,
              const int* __restrict__ rowptr, const int* __restrict__ col,
              __half* __restrict__ agg, int N)
{
    constexpr int CPE = F / 8;
    int tid = blockIdx.x * 256 + threadIdx.x;
    int node = tid / CPE, c = tid % CPE;
    if (node >= N) return;
    int n = cnt[node], rp = rowptr[node];
    float acc[8] = {0.f, 0.f, 0.f, 0.f, 0.f, 0.f, 0.f, 0.f};
    for (int j = 0; j < n; ++j) {
        int s = col[rp + j];
        if (F32SRC) {
            const float* p = (const float*)hsrc + (size_t)s * F + c * 8;
            float4 a = *(const float4*)p, b = *(const float4*)(p + 4);
            float xv[8] = {a.x, a.y, a.z, a.w, b.x, b.y, b.z, b.w};
#pragma unroll
            for (int i = 0; i < 8; ++i) acc[i] += RELU ? fmaxf(xv[i], 0.f) : xv[i];
        } else {
            u16 vs[8] __attribute__((aligned(16)));
            *(uint4*)vs = *(const uint4*)((const u16*)hsrc + (size_t)s * F + c * 8);
#pragma unroll
            for (int i = 0; i < 8; ++i) {
                float x = b2f(vs[i]);
                acc[i] += RELU ? fmaxf(x, 0.f) : x;
            }
        }
    }
    __half ob[8] __attribute__((aligned(16)));
#pragma unroll
    for (int i = 0; i < 8; ++i) ob[i] = __float2half(acc[i]);
    *(uint4*)(agg + (size_t)node * F + c * 8) = *(const uint4*)ob;
}

// transpose + f32->bf16 convert: out[n*K+k] = bf16(in[k*N+n])   (weights, tiny)
__global__ void k_T(const float* __restrict__ in, u16* __restrict__ out, int K, int N)
{
    int t = blockIdx.x * 256 + threadIdx.x;
    if (t >= K * N) return;
    int n = t / K, k = t % K;
    out[t] = f2b(in[k * N + n]);
}

// ---------------------------------------------------------------------------
// Fused GIN MLP v2: Hout(own 64 rows) = relu((relu?(A)+agg)@Wa+ba)@Wb+bb
// Block 64 rows x 256 cols, 4 waves side-by-side in n; wave = 64x64, 4x4 frags.
// A chunk + full B chunk (256n x 32k) staged in LDS each iter (stride 40 u16).
// Hidden tile in LDS (stride 264). In-place H safe (block touches own rows).
// ---------------------------------------------------------------------------
template<int K, bool RELUIN, bool AF32>
__global__ __launch_bounds__(256)
void k_gin(const void* Ain, const __half* __restrict__ agg,
           const u16* __restrict__ WaT, const float* __restrict__ ba,
           const u16* __restrict__ WbT, const float* __restrict__ bb,
           u16* Hout)
{
    __shared__ u16 As[64 * 40];      //  5.1 KB
    __shared__ u16 Bs[256 * 40];     // 20.5 KB
    __shared__ u16 Hs[64 * 264];     // 33.8 KB

    const int tid = threadIdx.x, lane = tid & 63, wave = tid >> 6;
    const int bm0 = blockIdx.x * 64;
    const int fm = lane & 15, fk = (lane >> 4) * 8;
    const int lc = lane & 15, lr = (lane >> 4) * 4;
    const int cw0 = wave * 64;                    // wave col base
    const int sr = tid >> 2, sc = tid & 3;        // A staging coords

    f32x4 acc[4][4];
#pragma unroll
    for (int r = 0; r < 4; ++r)
#pragma unroll
        for (int c = 0; c < 4; ++c) acc[r][c] = (f32x4){0.f, 0.f, 0.f, 0.f};

    // ---- phase 1: hidden = relu((relu?(A)+agg) @ Wa + ba) ----
    for (int k0 = 0; k0 < K; k0 += 32) {
        // A_eff staging: 8 elems/thread
        const size_t aoff = (size_t)(bm0 + sr) * K + k0 + sc * 8;
        float av[8];
        if (AF32) {
            const float* p = (const float*)Ain + aoff;
            float4 a = *(const float4*)p, b = *(const float4*)(p + 4);
            av[0]=a.x; av[1]=a.y; av[2]=a.z; av[3]=a.w;
            av[4]=b.x; av[5]=b.y; av[6]=b.z; av[7]=b.w;
        } else {
            u16 hb[8] __attribute__((aligned(16)));
            *(uint4*)hb = *(const uint4*)((const u16*)Ain + aoff);
#pragma unroll
            for (int i = 0; i < 8; ++i) av[i] = b2f(hb[i]);
        }
        __half ab[8] __attribute__((aligned(16)));
        *(uint4*)ab = *(const uint4*)(agg + aoff);
        u16 ob[8] __attribute__((aligned(16)));
#pragma unroll
        for (int i = 0; i < 8; ++i) {
            float v = av[i];
            if (RELUIN) v = fmaxf(v, 0.f);
            ob[i] = f2b(v + __half2float(ab[i]));
        }
        *(uint4*)&As[sr * 40 + sc * 8] = *(const uint4*)ob;
        // B staging: thread tid copies WaT row tid, k0..k0+32 (4x16B)
        {
            const uint4* wp = (const uint4*)(WaT + (size_t)tid * K + k0);
#pragma unroll
            for (int c = 0; c < 4; ++c)
                *(uint4*)&Bs[tid * 40 + c * 8] = wp[c];
        }
        __syncthreads();
        bf16x8 a[4], b[4];
#pragma unroll
        for (int r = 0; r < 4; ++r) a[r] = *(const bf16x8*)&As[(r * 16 + fm) * 40 + fk];
#pragma unroll
        for (int c = 0; c < 4; ++c) b[c] = *(const bf16x8*)&Bs[(cw0 + c * 16 + fm) * 40 + fk];
#pragma unroll
        for (int r = 0; r < 4; ++r)
#pragma unroll
            for (int c = 0; c < 4; ++c)
                acc[r][c] = __builtin_amdgcn_mfma_f32_16x16x32_bf16(a[r], b[c], acc[r][c], 0, 0, 0);
        __syncthreads();
    }
    // epilogue 1 -> LDS hidden (C/D layout: col=lane&15, row=(lane>>4)*4+i)
#pragma unroll
    for (int c = 0; c < 4; ++c) {
        const int col = cw0 + c * 16 + lc;
        const float bv = ba[col];
#pragma unroll
        for (int r = 0; r < 4; ++r)
#pragma unroll
            for (int i = 0; i < 4; ++i)
                Hs[(r * 16 + lr + i) * 264 + col] = f2b(fmaxf(acc[r][c][i] + bv, 0.f));
    }
    __syncthreads();

    // ---- phase 2: out = hidden @ Wb + bb ----
    f32x4 acc2[4][4];
#pragma unroll
    for (int r = 0; r < 4; ++r)
#pragma unroll
        for (int c = 0; c < 4; ++c) acc2[r][c] = (f32x4){0.f, 0.f, 0.f, 0.f};
    for (int k0 = 0; k0 < 256; k0 += 32) {
        {
            const uint4* wp = (const uint4*)(WbT + (size_t)tid * 256 + k0);
#pragma unroll
            for (int c = 0; c < 4; ++c)
                *(uint4*)&Bs[tid * 40 + c * 8] = wp[c];
        }
        __syncthreads();
        bf16x8 a[4], b[4];
#pragma unroll
        for (int r = 0; r < 4; ++r) a[r] = *(const bf16x8*)&Hs[(r * 16 + fm) * 264 + k0 + fk];
#pragma unroll
        for (int c = 0; c < 4; ++c) b[c] = *(const bf16x8*)&Bs[(cw0 + c * 16 + fm) * 40 + fk];
#pragma unroll
        for (int r = 0; r < 4; ++r)
#pragma unroll
            for (int c = 0; c < 4; ++c)
                acc2[r][c] = __builtin_amdgcn_mfma_f32_16x16x32_bf16(a[r], b[c], acc2[r][c], 0, 0, 0);
        __syncthreads();
    }
#pragma unroll
    for (int c = 0; c < 4; ++c) {
        const int col = cw0 + c * 16 + lc;
        const float bv = bb[col];
#pragma unroll
        for (int r = 0; r < 4; ++r)
#pragma unroll
            for (int i = 0; i < 4; ++i)
                Hout[(size_t)(bm0 + r * 16 + lr + i) * 256 + col] = f2b(acc2[r][c][i] + bv);
    }
}

// ---------------------------------------------------------------------------
// Classifier linear v2: C[f32] = leaky(A[bf16] @ WT^T), N=512 via 2 n-blocks.
// Same 4-wave 4x4 structure; K=256.
// ---------------------------------------------------------------------------
__global__ __launch_bounds__(256)
void k_lin(const u16* __restrict__ A, const u16* __restrict__ WT,
           float* __restrict__ C)
{
    __shared__ u16 As[64 * 40];
    __shared__ u16 Bs[256 * 40];
    const int tid = threadIdx.x, lane = tid & 63, wave = tid >> 6;
    const int bm0 = blockIdx.x * 64, bn0 = blockIdx.y * 256;
    const int fm = lane & 15, fk = (lane >> 4) * 8;
    const int lc = lane & 15, lr = (lane >> 4) * 4;
    const int cw0 = wave * 64;
    const int sr = tid >> 2, sc = tid & 3;

    f32x4 acc[4][4];
#pragma unroll
    for (int r = 0; r < 4; ++r)
#pragma unroll
        for (int c = 0; c < 4; ++c) acc[r][c] = (f32x4){0.f, 0.f, 0.f, 0.f};

    for (int k0 = 0; k0 < 256; k0 += 32) {
        *(uint4*)&As[sr * 40 + sc * 8] =
            *(const uint4*)(A + (size_t)(bm0 + sr) * 256 + k0 + sc * 8);
        {
            const uint4* wp = (const uint4*)(WT + (size_t)(bn0 + tid) * 256 + k0);
#pragma unroll
            for (int c = 0; c < 4; ++c)
                *(uint4*)&Bs[tid * 40 + c * 8] = wp[c];
        }
        __syncthreads();
        bf16x8 a[4], b[4];
#pragma unroll
        for (int r = 0; r < 4; ++r) a[r] = *(const bf16x8*)&As[(r * 16 + fm) * 40 + fk];
#pragma unroll
        for (int c = 0; c < 4; ++c) b[c] = *(const bf16x8*)&Bs[(cw0 + c * 16 + fm) * 40 + fk];
#pragma unroll
        for (int r = 0; r < 4; ++r)
#pragma unroll
            for (int c = 0; c < 4; ++c)
                acc[r][c] = __builtin_amdgcn_mfma_f32_16x16x32_bf16(a[r], b[c], acc[r][c], 0, 0, 0);
        __syncthreads();
    }
#pragma unroll
    for (int c = 0; c < 4; ++c) {
        const int col = bn0 + cw0 + c * 16 + lc;
#pragma unroll
        for (int r = 0; r < 4; ++r)
#pragma unroll
            for (int i = 0; i < 4; ++i) {
                float v = acc[r][c][i];
                v = (v >= 0.f) ? v : 0.01f * v;   // leaky
                C[(size_t)(bm0 + r * 16 + lr + i) * 512 + col] = v;
            }
    }
}

// ---------------------------------------------------------------------------
// Head kernels (f32)
// ---------------------------------------------------------------------------
__global__ void k_pool(const u16* __restrict__ H, u16* __restrict__ Xc)
{
    int c = blockIdx.x, f = threadIdx.x;          // 8192 blocks x 256
    const u16* p = H + (size_t)c * 25 * 256 + f;
    float s = 0.f;
#pragma unroll
    for (int j = 0; j < 25; ++j) s += b2f(p[j * 256]);
    Xc[(size_t)c * 256 + f] = f2b(s / 25.0f);
}

__global__ void k_setpool(const float* __restrict__ T, float* __restrict__ Tp)
{
    int tid = blockIdx.x * 256 + threadIdx.x;     // 4096*64
    int b = tid >> 6, s = tid & 63;
    float acc = 0.f;
#pragma unroll
    for (int c = 0; c < 2; ++c) {
        const float* row = T + ((size_t)(b * 2 + c)) * 512 + s;
        float mx = row[0];
#pragma unroll
        for (int m = 1; m < 8; ++m) mx = fmaxf(mx, row[m * 64]);
        acc += mx;
    }
    Tp[tid] = acc;
}

__global__ void k_fc1(const float* __restrict__ Tp, const float* __restrict__ w,
                      const float* __restrict__ b, float* __restrict__ T1)
{
    int tid = blockIdx.x * 256 + threadIdx.x;     // 4096*32
    int bb = tid >> 5, j = tid & 31;
    float s = b[j];
#pragma unroll
    for (int k = 0; k < 64; ++k) s += Tp[bb * 64 + k] * w[k * 32 + j];
    T1[tid] = s;
}

__global__ void k_bnstats(const float* __restrict__ T1, float* __restrict__ stats)
{
    __shared__ float r1[256], r2[256];
    const int j = blockIdx.x, t = threadIdx.x;    // 32 blocks
    float s = 0.f, ss = 0.f;
    for (int b = t; b < 4096; b += 256) {
        float v = T1[b * 32 + j];
        s += v; ss += v * v;
    }
    r1[t] = s; r2[t] = ss;
    __syncthreads();
    for (int off = 128; off > 0; off >>= 1) {
        if (t < off) { r1[t] += r1[t + off]; r2[t] += r2[t + off]; }
        __syncthreads();
    }
    if (t == 0) {
        float mu  = r1[0] * (1.f / 4096.f);
        float var = r2[0] * (1.f / 4096.f) - mu * mu;
        stats[j]      = mu;
        stats[32 + j] = 1.f / sqrtf(var + 1e-5f);
    }
}

__global__ void k_head(const float* __restrict__ T1, const float* __restrict__ stats,
                       const float* __restrict__ g, const float* __restrict__ bb,
                       const float* __restrict__ w2, const float* __restrict__ b2,
                       float* __restrict__ out)
{
    const int b = blockIdx.x * 256 + threadIdx.x; // 4096
    float l0 = b2[0], l1 = b2[1];
#pragma unroll
    for (int j = 0; j < 32; ++j) {
        float v = (T1[b * 32 + j] - stats[j]) * stats[32 + j] * g[j] + bb[j];
        v = (v >= 0.f) ? v : 0.01f * v;
        l0 += v * w2[j * 2];
        l1 += v * w2[j * 2 + 1];
    }
    float mx  = fmaxf(l0, l1);
    float lse = mx + logf(expf(l0 - mx) + expf(l1 - mx));
    out[b * 2]     = l0 - lse;
    out[b * 2 + 1] = l1 - lse;
}

// ---------------------------------------------------------------------------
extern "C" void kernel_launch(void* const* d_in, const int* in_sizes, int n_in,
                              void* d_out, int out_size, void* d_ws, size_t ws_size,
                              hipStream_t stream)
{
    (void)n_in; (void)out_size; (void)ws_size;
    constexpr int NN = 204800, NCOMP = 8192, NGRAPH = 4096;

    const float* x    = (const float*)d_in[0];
    const float* w0a  = (const float*)d_in[1];
    const float* b0a  = (const float*)d_in[2];
    const float* w0b  = (const float*)d_in[3];
    const float* b0b  = (const float*)d_in[4];
    const float* wra  = (const float*)d_in[5];
    const float* bra  = (const float*)d_in[6];
    const float* wrb  = (const float*)d_in[7];
    const float* brb  = (const float*)d_in[8];
    const float* Wc   = (const float*)d_in[9];
    const float* f1w  = (const float*)d_in[10];
    const float* f1b  = (const float*)d_in[11];
    const float* bng  = (const float*)d_in[12];
    const float* bnb  = (const float*)d_in[13];
    const float* f2w  = (const float*)d_in[14];
    const float* f2bb = (const float*)d_in[15];
    const int* ei   = (const int*)d_in[16];
    const int  E    = in_sizes[16] / 2;           // 409600
    const int* src  = ei;
    const int* dst  = ei + E;

    // ---- workspace layout (~205 MiB) ----
    char* ws = (char*)d_ws;
    __half* AGG = (__half*)ws;                               // [N,256] f16, 100 MiB
    u16*    H   = (u16*)(ws + (size_t)104857600);            // [N,256] bf16, 100 MiB
    u16*    wt  = (u16*)(ws + (size_t)209715200);            // transposed bf16 weights, 1 MiB
    u16 *WT0 = wt, *WT1 = wt + 65536, *WT2 = wt + 131072, *WT3 = wt + 196608,
        *WT4 = wt + 262144, *WT5 = wt + 327680, *WT6 = wt + 393216;
    // CSR arrays after weights:
    char* csr = ws + (size_t)210763776;
    int* cnt    = (int*)csr;                                 // [N]
    int* rowptr = (int*)(csr + 819200);                      // [N]
    int* cursor = (int*)(csr + 1638400);                     // [N]
    int* col    = (int*)(csr + 2457600);                     // [E]
    int* bsum   = (int*)(csr + 4096000);                     // [1024]
    int* bscan  = (int*)(csr + 4100096);                     // [1024]
    // head scratch reuses dead AGG region:
    u16*   Xc    = (u16*)ws;                                 // [8192,256] bf16
    float* Tfull = (float*)(ws + (size_t)16777216);          // [8192,512] f32
    float* Tp    = (float*)(ws + (size_t)33554432);          // [4096,64]
    float* T1    = (float*)(ws + (size_t)41943040);          // [4096,32]
    float* stats = (float*)(ws + (size_t)46137344);          // mu[32], rstd[32]

    const dim3 blk(256);
    const int NB = NN / 256;                                  // 800 scan blocks

    // ---- CSR build (once, reused by all 3 layers) ----
    hipMemsetAsync(cnt, 0, NN * 4, stream);
    k_count<<<(E + 255) / 256, blk, 0, stream>>>(dst, cnt, E);
    k_scan1<<<NB, blk, 0, stream>>>(cnt, rowptr, bsum, NN);
    k_scan2<<<1, blk, 0, stream>>>(bsum, bscan, NB);
    k_scan3<<<NB, blk, 0, stream>>>(rowptr, bscan, cursor, NN);
    k_fill<<<(E + 255) / 256, blk, 0, stream>>>(src, dst, cursor, col, E);

    // ---- pre-transpose weights (f32 -> bf16) ----
    k_T<<<128, blk, 0, stream>>>(w0a, WT0, 128, 256);
    k_T<<<256, blk, 0, stream>>>(w0b, WT1, 256, 256);
    k_T<<<256, blk, 0, stream>>>(wra,          WT2, 256, 256);
    k_T<<<256, blk, 0, stream>>>(wra + 65536,  WT3, 256, 256);
    k_T<<<256, blk, 0, stream>>>(wrb,          WT4, 256, 256);
    k_T<<<256, blk, 0, stream>>>(wrb + 65536,  WT5, 256, 256);
    k_T<<<512, blk, 0, stream>>>(Wc, WT6, 256, 512);

    // ---- layer 0 (K=128, A = x f32, no relu) ----
    k_gather<128, false, true><<<(NN * 16) / 256, blk, 0, stream>>>(x, cnt, rowptr, col, AGG, NN);
    k_gin<128, false, true><<<NN / 64, blk, 0, stream>>>(x, AGG, WT0, b0a, WT1, b0b, H);

    // ---- layers 1..2 (K=256, A = H bf16, relu on layer input) ----
    const u16* WA[2] = {WT2, WT3};
    const u16* WB[2] = {WT4, WT5};
    for (int l = 0; l < 2; ++l) {
        k_gather<256, true, false><<<(NN * 32) / 256, blk, 0, stream>>>(H, cnt, rowptr, col, AGG, NN);
        k_gin<256, true, false><<<NN / 64, blk, 0, stream>>>(
            H, AGG, WA[l], bra + (size_t)l * 256, WB[l], brb + (size_t)l * 256, H);
    }

    // ---- head ----
    k_pool<<<NCOMP, blk, 0, stream>>>(H, Xc);
    k_lin<<<dim3(NCOMP / 64, 2), blk, 0, stream>>>(Xc, WT6, Tfull);
    k_setpool<<<(NGRAPH * 64) / 256, blk, 0, stream>>>(Tfull, Tp);
    k_fc1<<<(NGRAPH * 32) / 256, blk, 0, stream>>>(Tp, f1w, f1b, T1);
    k_bnstats<<<32, blk, 0, stream>>>(T1, stats);
    k_head<<<NGRAPH / 256, blk, 0, stream>>>(T1, stats, bng, bnb, f2w, f2bb, (float*)d_out);
}